// Round 1
// 624.403 us; speedup vs baseline: 1.1572x; 1.1572x over previous
//
#include <hip/hip_runtime.h>

// Problem constants
#define BB    16
#define CIN   32
#define LEN   1024
#define TT    64
#define COUT  64
#define KK    3

// Tiling
#define TL       16                  // l per block -> 64x16 = 1024 blocks (4/CU)
#define HALO     (TL + 2)            // 18 rows incl. conv halo
#define NTHREADS 256                 // 4 waves; thread = (co-group[4b], l[4b])
#define CO_PER   4                   // co per thread (16 groups x 4 = 64)
#define NGRAN    (CIN * HALO * 4)    // 2304 16-B granules: full 64-B t-chunk rows
#define NRND     (NGRAN / 64)        // 36 wave-rounds per stage
#define SPT      (NRND / 4)          // 9 granules per thread per stage (exact)

// INVARIANT (bit-exact vs np ref, proven in earlier rounds): per output cell
// the conv sum is ONE sequential fmaf chain, k outer (0..2), ci inner (0..31),
// acc=0; LIF fp32: s=pot+a; p=s*0.9f; spk=(p>=0.25f); pot=spk?0:p.

__global__ __launch_bounds__(NTHREADS, 4)
void snn_v4(const float* __restrict__ x, const float* __restrict__ w,
            float* __restrict__ out) {
    // single buffer; rows are 64 B (4 granules), granule position XOR-swizzled
    // by ((row>>1)&3) so stride-64B reads hit 8 distinct bank-starts (2-way).
    __shared__ float4 xs[NGRAN];     // 36864 B -> 4 blocks/CU

    const int tid  = threadIdx.x;
    const int l    = tid & (TL - 1);
    const int g    = tid >> 4;               // 0..15 co-group
    const int co0  = g * CO_PER;
    const int lane = tid & 63;
    const int wv   = tid >> 6;               // wave 0..3
    const int l0   = blockIdx.x * TL;
    const int b    = blockIdx.y;

    const float* xb = x + (size_t)b * CIN * LEN * TT;
    const float* wb = w + co0 * (CIN * KK);  // weights via L1 imm-offset loads

    // ---- staging descriptors (static per thread; advance 64 B per stage)
    int goff[SPT], loff[SPT];
    unsigned okb = 0u;
    #pragma unroll
    for (int s = 0; s < SPT; ++s) {
        const int G   = (wv + s * 4) * 64 + lane;    // < 2304, exact coverage
        const int ci  = G / (HALO * 4);
        const int rem = G - ci * (HALO * 4);
        const int row = rem >> 2;
        const int h   = rem & 3;                     // 16-B granule within 64-B
        const int lg  = l0 - 1 + row;
        const bool ok = (lg >= 0) && (lg < LEN);
        okb |= ok ? (1u << s) : 0u;
        goff[s] = (ci * LEN + (ok ? lg : 0)) * TT + h * 4;           // floats
        loff[s] = ci * (HALO * 4) + row * 4 + (h ^ ((row >> 1) & 3)); // XOR-swz
    }

    float    pot[CO_PER] = {0.f, 0.f, 0.f, 0.f};
    unsigned mlo[CO_PER] = {0u, 0u, 0u, 0u};     // spike bits t=0..31
    unsigned mhi[CO_PER] = {0u, 0u, 0u, 0u};     // spike bits t=32..63
    float4   tmp[SPT];

    auto issue_loads = [&](int sc) {
        #pragma unroll
        for (int s = 0; s < SPT; ++s) {
            tmp[s] = make_float4(0.f, 0.f, 0.f, 0.f);
            if (okb & (1u << s))
                tmp[s] = *(const float4*)(xb + goff[s] + sc * 16);
        }
    };

    // one 8-t substage: conv (EXACT chain: k outer, ci inner) + LIF + mask bits
    auto substage = [&](int sub, int sc) {
        float acc[CO_PER][8];
        #pragma unroll
        for (int j = 0; j < CO_PER; ++j)
            #pragma unroll
            for (int i = 0; i < 8; ++i) acc[j][i] = 0.f;

        #pragma unroll
        for (int k = 0; k < KK; ++k) {
            const int rowk = l + k;
            const int sw   = (rowk >> 1) & 3;
            const int sA   = rowk * 4 + ((sub * 2)     ^ sw);
            const int sB   = rowk * 4 + ((sub * 2 + 1) ^ sw);
            #pragma unroll 1
            for (int cic = 0; cic < CIN / 4; ++cic) {
                #pragma unroll
                for (int c4 = 0; c4 < 4; ++c4) {
                    const int ci = cic * 4 + c4;
                    const float4 xa = xs[ci * (HALO * 4) + sA];
                    const float4 xc = xs[ci * (HALO * 4) + sB];
                    #pragma unroll
                    for (int j = 0; j < CO_PER; ++j) {
                        const float wj = wb[j * (CIN * KK) + ci * KK + k];
                        acc[j][0] = fmaf(xa.x, wj, acc[j][0]);
                        acc[j][1] = fmaf(xa.y, wj, acc[j][1]);
                        acc[j][2] = fmaf(xa.z, wj, acc[j][2]);
                        acc[j][3] = fmaf(xa.w, wj, acc[j][3]);
                        acc[j][4] = fmaf(xc.x, wj, acc[j][4]);
                        acc[j][5] = fmaf(xc.y, wj, acc[j][5]);
                        acc[j][6] = fmaf(xc.z, wj, acc[j][6]);
                        acc[j][7] = fmaf(xc.w, wj, acc[j][7]);
                    }
                }
            }
        }

        #pragma unroll
        for (int j = 0; j < CO_PER; ++j) {
            unsigned sb = 0u;
            #pragma unroll
            for (int i = 0; i < 8; ++i) {
                const float s  = pot[j] + acc[j][i];
                const float p  = s * 0.9f;
                const bool  sp = (p >= 0.25f);
                sb |= sp ? (1u << i) : 0u;
                pot[j] = sp ? 0.0f : p;
            }
            const unsigned sh = (unsigned)((sc & 1) * 16 + sub * 8);
            if (sc < 2) mlo[j] |= sb << sh;
            else        mhi[j] |= sb << sh;
        }
    };

    #pragma unroll 1
    for (int sc = 0; sc < 4; ++sc) {       // stage = 16 t (full 64-B sectors)
        issue_loads(sc);                   // overlaps other waves' compute tail
        __syncthreads();                   // previous stage's readers done
        #pragma unroll
        for (int s = 0; s < SPT; ++s) xs[loff[s]] = tmp[s];
        __syncthreads();                   // tile ready
        substage(0, sc);
        substage(1, sc);
    }

    // ---- epilogue: expand bitmasks -> full 256-B contiguous rows per (co,l)
    float* outb = out + (size_t)b * COUT * LEN * TT;
    #pragma unroll
    for (int j = 0; j < CO_PER; ++j) {
        float* dst = outb + ((size_t)(co0 + j) * LEN + (l0 + l)) * TT;
        #pragma unroll
        for (int tq = 0; tq < 16; ++tq) {
            const unsigned word = (tq < 8) ? mlo[j] : mhi[j];
            const unsigned nib  = word >> ((tq & 7) * 4);
            float4 v;
            v.x = (nib & 1u) ? 1.0f : 0.0f;
            v.y = (nib & 2u) ? 1.0f : 0.0f;
            v.z = (nib & 4u) ? 1.0f : 0.0f;
            v.w = (nib & 8u) ? 1.0f : 0.0f;
            *(float4*)(dst + tq * 4) = v;
        }
    }
}

extern "C" void kernel_launch(void* const* d_in, const int* in_sizes, int n_in,
                              void* d_out, int out_size, void* d_ws, size_t ws_size,
                              hipStream_t stream) {
    const float* x = (const float*)d_in[0];   // (16, 32, 1024, 64) fp32
    const float* w = (const float*)d_in[1];   // (64, 32, 3) fp32
    float* out = (float*)d_out;               // (16, 64, 1024, 64) fp32
    (void)d_ws; (void)ws_size; (void)in_sizes; (void)n_in; (void)out_size;

    hipLaunchKernelGGL(snn_v4, dim3(LEN / TL, BB), dim3(NTHREADS),
                       0, stream, x, w, out);
}